// Round 10
// baseline (55.241 us; speedup 1.0000x reference)
//
#include <hip/hip_runtime.h>
#include <hip/hip_bf16.h>
#include <math.h>

#define BB 4
#define CCH 128     // channels
#define HH 64
#define WW 256
#define RR 8
#define KWIN 17
#define TW 32       // output w-tile (K2)
#define TWH 48      // TW + 2R
#define NTHREADS 256
#define PIT 136     // fBt pitch (shorts)
#define STP 36      // St pitch (floats)
#define PTP 56      // K2 Pt pitch (shorts): 28 dw -> 2-way banks on b128 reads
#define MROWS 144

// ---- d_ws layout (bytes) ----
#define SZ_BHWC (BB * HH * WW * CCH * 2)          // 16,777,216
#define OFF_FT  65536
#define OFF_GT  (OFF_FT + SZ_BHWC)
#define OFF_FN  (OFF_GT + SZ_BHWC)
#define OFF_UB  (OFF_FN + SZ_BHWC)
#define WS_NEED ((size_t)OFF_UB + (size_t)(BB * HH * WW * 4))

typedef __attribute__((ext_vector_type(8))) short short8;
typedef __attribute__((ext_vector_type(4))) short short4v;
typedef __attribute__((ext_vector_type(4))) float f32x4;

__device__ __forceinline__ short f2bf(float x) {
    union { __hip_bfloat16 b; short s; } u;
    u.b = __float2bfloat16(x);
    return u.s;
}

// ---- prep: M' bf16 [144][128] = [Wq^T Wk ; (Wk^T bq)^T ; zeros] -------------
__global__ __launch_bounds__(128)
void prep_kernel(const float* __restrict__ Wq, const float* __restrict__ bq,
                 const float* __restrict__ Wk, short* __restrict__ Mp)
{
    const int r = blockIdx.x;      // 0..143
    const int c = threadIdx.x;     // 0..127
    float acc = 0.f;
    if (r < CCH) {
        #pragma unroll 4
        for (int j = 0; j < CCH; ++j)
            acc = fmaf(Wq[j * CCH + r], Wk[j * CCH + c], acc);
    } else if (r == CCH) {
        #pragma unroll 4
        for (int o = 0; o < CCH; ++o)
            acc = fmaf(bq[o], Wk[o * CCH + c], acc);
    }
    Mp[r * CCH + c] = f2bf(acc);
}

// ---- K1: streaming transform (no halo). Emits fT, gT, fN (bf16) + ubias -----
__global__ __launch_bounds__(NTHREADS, 4)
void k1_transform(const float* __restrict__ feature,
                  const float* __restrict__ position,
                  const short* __restrict__ Mp,
                  short* __restrict__ fTg, short* __restrict__ gTg,
                  short* __restrict__ fNg, float* __restrict__ ubg)
{
    __shared__ __align__(16) short fBt[64][PIT];   // f^T [w][c], 17408 B

    const int t    = threadIdx.x;
    const int wid  = t >> 6;
    const int lane = t & 63;
    const int lrow = lane & 15;
    const int lgrp = lane >> 4;

    int blk = blockIdx.x;                 // 1024 blocks, %8==0 -> bijective
    blk = (blk & 7) * 128 + (blk >> 3);
    const int wt = blk & 3;               // W/64 = 4
    const int bh = blk >> 2;
    const int h  = bh & (HH - 1);
    const int b  = bh >> 6;
    const int w0 = wt * 64;
    const int base = ((b * CCH) * HH + h) * WW;
    const int bhw  = (b * HH + h) * WW;

    // M-fragments (bf16 direct 16B loads)
    const int mrow = wid * 32;
    short8 Mf[2][4];
    #pragma unroll
    for (int mf = 0; mf < 2; ++mf)
        #pragma unroll
        for (int kk = 0; kk < 4; ++kk)
            Mf[mf][kk] = *(const short8*)(Mp + (mrow + mf * 16 + lrow) * CCH
                                             + kk * 32 + lgrp * 8);
    short8 Mf2[4];
    if (wid == 3) {
        #pragma unroll
        for (int kk = 0; kk < 4; ++kk)
            Mf2[kk] = *(const short8*)(Mp + (CCH + lrow) * CCH + kk * 32 + lgrp * 8);
    }

    // stage: 2048 quads (128c x 16wq); c = idx>>4, wq = idx&15 (coalesced rows)
    #pragma unroll
    for (int i = 0; i < 8; ++i) {
        const int idx = i * NTHREADS + t;
        const int c  = idx >> 4;
        const int wq = idx & 15;
        const int off = base + c * (HH * WW) + w0 + wq * 4;
        const float4 fa = *(const float4*)(feature + off);
        const float4 pa = *(const float4*)(position + off);
        short4v s4;
        s4[0] = f2bf(fa.x + pa.x); s4[1] = f2bf(fa.y + pa.y);
        s4[2] = f2bf(fa.z + pa.z); s4[3] = f2bf(fa.w + pa.w);
        fBt[wq * 4 + 0][c] = s4[0];
        fBt[wq * 4 + 1][c] = s4[1];
        fBt[wq * 4 + 2][c] = s4[2];
        fBt[wq * 4 + 3][c] = s4[3];
        *(short4v*)(fNg + ((b * CCH + c) * HH + h) * WW + w0 + wq * 4) = s4;
    }
    __syncthreads();

    // fT copy-out: row r = t>>2, 64B chunk (t&3)*32 shorts (coalesced 256B rows)
    {
        const int r  = t >> 2;
        const int ch = (t & 3) * 32;
        short* dst = fTg + (bhw + w0 + r) * CCH + ch;
        #pragma unroll
        for (int q = 0; q < 4; ++q)
            *(short8*)(dst + q * 8) = *(const short8*)&fBt[r][ch + q * 8];
    }

    // Phase B: g = M f (each wave: 32 M-rows x 64 w), wave3 adds u-row
    f32x4 acc[2][4];
    #pragma unroll
    for (int mf = 0; mf < 2; ++mf)
        #pragma unroll
        for (int nf = 0; nf < 4; ++nf)
            acc[mf][nf] = (f32x4){0.f, 0.f, 0.f, 0.f};
    f32x4 acc2[4];
    #pragma unroll
    for (int nf = 0; nf < 4; ++nf) acc2[nf] = (f32x4){0.f, 0.f, 0.f, 0.f};

    #pragma unroll
    for (int kk = 0; kk < 4; ++kk) {
        short8 bfr[4];
        #pragma unroll
        for (int nf = 0; nf < 4; ++nf)
            bfr[nf] = *(const short8*)&fBt[nf * 16 + lrow][kk * 32 + lgrp * 8];
        #pragma unroll
        for (int mf = 0; mf < 2; ++mf)
            #pragma unroll
            for (int nf = 0; nf < 4; ++nf)
                acc[mf][nf] = __builtin_amdgcn_mfma_f32_16x16x32_bf16(
                    Mf[mf][kk], bfr[nf], acc[mf][nf], 0, 0, 0);
        if (wid == 3) {
            #pragma unroll
            for (int nf = 0; nf < 4; ++nf)
                acc2[nf] = __builtin_amdgcn_mfma_f32_16x16x32_bf16(
                    Mf2[kk], bfr[nf], acc2[nf], 0, 0, 0);
        }
    }

    // gT writeback: row w = w0+nf*16+lrow, cols mrow+mf*16+lgrp*4 (8B stores)
    #pragma unroll
    for (int mf = 0; mf < 2; ++mf)
        #pragma unroll
        for (int nf = 0; nf < 4; ++nf) {
            short4v s;
            #pragma unroll
            for (int reg = 0; reg < 4; ++reg)
                s[reg] = f2bf(acc[mf][nf][reg]);
            *(short4v*)(gTg + (bhw + w0 + nf * 16 + lrow) * CCH
                            + mrow + mf * 16 + lgrp * 4) = s;
        }
    if (wid == 3 && lgrp == 0) {
        const float isc = 0.08838834764831845f;
        #pragma unroll
        for (int nf = 0; nf < 4; ++nf)
            ubg[bhw + w0 + nf * 16 + lrow] = acc2[nf][0] * isc;
    }
}

// ---- K2: local attention. Operands direct from bf16 arrays; 2 barriers. -----
__global__ __launch_bounds__(NTHREADS, 8)
void k2_attn(const short* __restrict__ fTg, const short* __restrict__ gTg,
             const short* __restrict__ fNg, const float* __restrict__ ubg,
             float* __restrict__ out)
{
    __shared__ __align__(16) float St[TWH][STP];   // 6912 B  S^T [wl'][w]
    __shared__ __align__(16) short Pt[33][PTP];    // 3696 B  P [w][wl] (+guard row)
    __shared__ float ubl[TWH];                     //  192 B
                                                   // ~10.8 KB -> 8 blocks/CU

    const int t    = threadIdx.x;
    const int wid  = t >> 6;
    const int lane = t & 63;
    const int lrow = lane & 15;
    const int lgrp = lane >> 4;

    int blk = blockIdx.x;                 // 2048 blocks
    blk = (blk & 7) * 256 + (blk >> 3);
    const int wt = blk & 7;
    const int bh = blk >> 3;
    const int h  = bh & (HH - 1);
    const int b  = bh >> 6;
    const int w0 = wt * TW - RR;
    const int bhw  = (b * HH + h) * WW;
    const int base = ((b * CCH) * HH + h) * WW;

    if (t < TWH) {
        const int w = w0 + t;
        ubl[t] = (w >= 0 && w < WW) ? ubg[bhw + w] : 0.f;
    }

    const short8 z8 = {0,0,0,0,0,0,0,0};

    // ---- Phase C: S^T = (f^T g)/sqrt(C); waves 0-2. wave3 zeros Pt. ----------
    if (wid < 3) {
        const int nf = wid;
        const int wl = nf * 16 + lrow;          // wl' 0..47
        const int wg = w0 + wl;
        const bool inb = (wg >= 0 && wg < WW);
        f32x4 s0 = {0.f,0.f,0.f,0.f}, s1 = s0;
        #pragma unroll
        for (int kk = 0; kk < 4; ++kk) {
            const int ko = kk * 32 + lgrp * 8;
            const short8 a0 = *(const short8*)(fTg + (bhw + wt * TW + lrow) * CCH + ko);
            const short8 a1 = *(const short8*)(fTg + (bhw + wt * TW + 16 + lrow) * CCH + ko);
            const short8 bb = inb ? *(const short8*)(gTg + (bhw + wg) * CCH + ko) : z8;
            s0 = __builtin_amdgcn_mfma_f32_16x16x32_bf16(a0, bb, s0, 0, 0, 0);
            s1 = __builtin_amdgcn_mfma_f32_16x16x32_bf16(a1, bb, s1, 0, 0, 0);
        }
        const float isc = 0.08838834764831845f;
        *(f32x4*)&St[wl][lgrp * 4]      = s0 * isc;
        *(f32x4*)&St[wl][16 + lgrp * 4] = s1 * isc;
    } else {
        short* p = &Pt[0][0];
        #pragma unroll
        for (int i = 0; i < 4; ++i) {
            const int q8 = i * 64 + lane;       // 231 short8 chunks
            if (q8 < (33 * PTP) / 8) *(short8*)(p + q8 * 8) = z8;
        }
    }
    __syncthreads();

    // ---- softmax over 17 taps (4 threads/row) -------------------------------
    if (t < TW * 4) {
        const int w = t >> 2, g = t & 3;
        const int nt = (g == 0) ? 5 : 4;        // taps j = g+4i, plus j=16 for g==0
        float sv[5];
        float mx = -3.0e38f;
        #pragma unroll
        for (int i = 0; i < 5; ++i) {
            if (i < nt) {
                const int j = (i == 4) ? 16 : (g + i * 4);
                sv[i] = St[w + j][w] + ubl[w + j];
                mx = fmaxf(mx, sv[i]);
            }
        }
        mx = fmaxf(mx, __shfl_xor(mx, 1, 4));
        mx = fmaxf(mx, __shfl_xor(mx, 2, 4));
        float sum = 0.f;
        #pragma unroll
        for (int i = 0; i < 5; ++i)
            if (i < nt) { sv[i] = __expf(sv[i] - mx); sum += sv[i]; }
        sum += __shfl_xor(sum, 1, 4);
        sum += __shfl_xor(sum, 2, 4);
        const float inv = 1.f / sum;
        #pragma unroll
        for (int i = 0; i < 5; ++i)
            if (i < nt) {
                const int j = (i == 4) ? 16 : (g + i * 4);
                Pt[w][w + j] = f2bf(sv[i] * inv);
            }
    }
    __syncthreads();

    // ---- Phase D: out = f . P^T (A from fN global, 8-run zero predicates) ---
    {
        const int cb = wid * 32;
        f32x4 d00 = {0.f,0.f,0.f,0.f}, d01 = d00, d10 = d00, d11 = d00;
        #pragma unroll
        for (int kk = 0; kk < 2; ++kk) {
            const int koff = kk * 32 + lgrp * 8;
            const bool live = (koff < TWH);
            const int w = w0 + koff;                    // multiple of 8
            const bool inb = live && (w >= 0) && (w < WW);
            short8 a0 = z8, a1 = z8, b0 = z8, b1 = z8;
            if (inb) {
                a0 = *(const short8*)(fNg + ((b * CCH + cb + lrow) * HH + h) * WW + w);
                a1 = *(const short8*)(fNg + ((b * CCH + cb + 16 + lrow) * HH + h) * WW + w);
            }
            if (live) {
                b0 = *(const short8*)&Pt[lrow][koff];
                b1 = *(const short8*)&Pt[16 + lrow][koff];
            }
            d00 = __builtin_amdgcn_mfma_f32_16x16x32_bf16(a0, b0, d00, 0, 0, 0);
            d01 = __builtin_amdgcn_mfma_f32_16x16x32_bf16(a0, b1, d01, 0, 0, 0);
            d10 = __builtin_amdgcn_mfma_f32_16x16x32_bf16(a1, b0, d10, 0, 0, 0);
            d11 = __builtin_amdgcn_mfma_f32_16x16x32_bf16(a1, b1, d11, 0, 0, 0);
        }
        const int wbase = wt * TW;
        #pragma unroll
        for (int reg = 0; reg < 4; ++reg) {
            const int c0 = cb + lgrp * 4 + reg;
            out[base + c0 * (HH * WW)        + wbase + lrow]      = d00[reg];
            out[base + c0 * (HH * WW)        + wbase + 16 + lrow] = d01[reg];
            out[base + (c0 + 16) * (HH * WW) + wbase + lrow]      = d10[reg];
            out[base + (c0 + 16) * (HH * WW) + wbase + 16 + lrow] = d11[reg];
        }
    }
}

// ================== fallback: round-9 fused kernel (proven, 40 µs) ==========
#define FAPF 48
#define PTPF 48
#define PT_HIF 5440
#define ST_IDX(r) (((r) >> 4) * 1088 + ((r) & 15) * 36)

__global__ __launch_bounds__(NTHREADS, 4)
void attn1d_fused(const float* __restrict__ feature,
                  const float* __restrict__ position,
                  const short* __restrict__ Mp,
                  float* __restrict__ out)
{
    __shared__ __align__(16) char uA[TWH * PIT * 2];
    __shared__ __align__(16) char uB[TWH * PIT * 2];
    __shared__ __align__(16) short fA[CCH][FAPF];
    __shared__ float ubias[TWH];
    short (*fBt)[PIT] = (short(*)[PIT])uA;
    short (*gT)[PIT]  = (short(*)[PIT])uB;
    float* Stp        = (float*)uB;
    short* uAs        = (short*)uA;

    const int t    = threadIdx.x;
    const int wid  = t >> 6;
    const int lane = t & 63;
    const int lrow = lane & 15;
    const int lgrp = lane >> 4;

    int blk = blockIdx.x;
    blk = (blk & 7) * 256 + (blk >> 3);
    const int wt = blk & 7;
    const int bh = blk >> 3;
    const int h  = bh & (HH - 1);
    const int b  = bh >> 6;
    const int w0 = wt * TW - RR;
    const int base = ((b * CCH) * HH + h) * WW;

    const int mrow = wid * 32;
    short8 Mf[2][4];
    #pragma unroll
    for (int mf = 0; mf < 2; ++mf)
        #pragma unroll
        for (int kk = 0; kk < 4; ++kk)
            Mf[mf][kk] = *(const short8*)(Mp + (mrow + mf * 16 + lrow) * CCH
                                             + kk * 32 + lgrp * 8);
    short8 Mf2[4];
    if (wid == 3) {
        #pragma unroll
        for (int kk = 0; kk < 4; ++kk)
            Mf2[kk] = *(const short8*)(Mp + (CCH + lrow) * CCH + kk * 32 + lgrp * 8);
    }

    #pragma unroll
    for (int i = 0; i < 6; ++i) {
        const int idx = i * NTHREADS + t;
        const int c  = idx / 12;
        const int wq = idx - c * 12;
        const int w  = w0 + wq * 4;
        float4 fv = {0.f, 0.f, 0.f, 0.f};
        if (w >= 0 && w < WW) {
            const int off = base + c * (HH * WW) + w;
            const float4 fa = *(const float4*)(feature + off);
            const float4 pa = *(const float4*)(position + off);
            fv.x = fa.x + pa.x; fv.y = fa.y + pa.y;
            fv.z = fa.z + pa.z; fv.w = fa.w + pa.w;
        }
        short4v s4;
        s4[0] = f2bf(fv.x); s4[1] = f2bf(fv.y); s4[2] = f2bf(fv.z); s4[3] = f2bf(fv.w);
        *(short4v*)&fA[c][wq * 4] = s4;
        fBt[wq * 4 + 0][c] = s4[0];
        fBt[wq * 4 + 1][c] = s4[1];
        fBt[wq * 4 + 2][c] = s4[2];
        fBt[wq * 4 + 3][c] = s4[3];
    }
    __syncthreads();

    {
        f32x4 acc[2][3];
        #pragma unroll
        for (int mf = 0; mf < 2; ++mf)
            #pragma unroll
            for (int nf = 0; nf < 3; ++nf)
                acc[mf][nf] = (f32x4){0.f, 0.f, 0.f, 0.f};
        f32x4 acc2[3];
        #pragma unroll
        for (int nf = 0; nf < 3; ++nf) acc2[nf] = (f32x4){0.f, 0.f, 0.f, 0.f};

        #pragma unroll
        for (int kk = 0; kk < 4; ++kk) {
            short8 bfr[3];
            #pragma unroll
            for (int nf = 0; nf < 3; ++nf)
                bfr[nf] = *(const short8*)&fBt[nf * 16 + lrow][kk * 32 + lgrp * 8];
            #pragma unroll
            for (int mf = 0; mf < 2; ++mf)
                #pragma unroll
                for (int nf = 0; nf < 3; ++nf)
                    acc[mf][nf] = __builtin_amdgcn_mfma_f32_16x16x32_bf16(
                        Mf[mf][kk], bfr[nf], acc[mf][nf], 0, 0, 0);
            if (wid == 3) {
                #pragma unroll
                for (int nf = 0; nf < 3; ++nf)
                    acc2[nf] = __builtin_amdgcn_mfma_f32_16x16x32_bf16(
                        Mf2[kk], bfr[nf], acc2[nf], 0, 0, 0);
            }
        }
        #pragma unroll
        for (int mf = 0; mf < 2; ++mf)
            #pragma unroll
            for (int nf = 0; nf < 3; ++nf) {
                short4v s;
                #pragma unroll
                for (int reg = 0; reg < 4; ++reg)
                    s[reg] = f2bf(acc[mf][nf][reg]);
                *(short4v*)&gT[nf * 16 + lrow][mrow + mf * 16 + lgrp * 4] = s;
            }
        if (wid == 3 && lgrp == 0) {
            const float isc = 0.08838834764831845f;
            #pragma unroll
            for (int nf = 0; nf < 3; ++nf)
                ubias[nf * 16 + lrow] = acc2[nf][0] * isc;
        }
    }
    __syncthreads();

    if (wid < 3) {
        const int nf = wid;
        f32x4 s0 = {0.f,0.f,0.f,0.f}, s1 = {0.f,0.f,0.f,0.f};
        #pragma unroll
        for (int kk = 0; kk < 4; ++kk) {
            const short8 a0 = *(const short8*)&fBt[RR + lrow     ][kk * 32 + lgrp * 8];
            const short8 a1 = *(const short8*)&fBt[RR + 16 + lrow][kk * 32 + lgrp * 8];
            const short8 bb = *(const short8*)&gT[nf * 16 + lrow][kk * 32 + lgrp * 8];
            s0 = __builtin_amdgcn_mfma_f32_16x16x32_bf16(a0, bb, s0, 0, 0, 0);
            s1 = __builtin_amdgcn_mfma_f32_16x16x32_bf16(a1, bb, s1, 0, 0, 0);
        }
        const float isc = 0.08838834764831845f;
        const int sb = ST_IDX(nf * 16 + lrow);
        *(f32x4*)&Stp[sb + lgrp * 4]      = s0 * isc;
        *(f32x4*)&Stp[sb + 16 + lgrp * 4] = s1 * isc;
    } else {
        const short8 z = {0,0,0,0,0,0,0,0};
        #pragma unroll
        for (int i = 0; i < 2; ++i) {
            const int q8 = i * 64 + lane;
            if (q8 < 96) {
                *(short8*)(uAs + q8 * 8) = z;
                *(short8*)(uAs + PT_HIF + q8 * 8) = z;
            }
        }
    }
    __syncthreads();

    if (t < TW * 4) {
        const int w = t >> 2, g = t & 3;
        const int nt = (g == 0) ? 5 : 4;
        const int prow = (w < 16) ? (w * PTPF) : (PT_HIF + (w - 16) * PTPF);
        float sv[5];
        float mx = -3.0e38f;
        #pragma unroll
        for (int i = 0; i < 5; ++i) {
            if (i < nt) {
                const int j = (i == 4) ? 16 : (g + i * 4);
                const int r = w + j;
                sv[i] = Stp[ST_IDX(r) + w] + ubias[r];
                mx = fmaxf(mx, sv[i]);
            }
        }
        mx = fmaxf(mx, __shfl_xor(mx, 1, 4));
        mx = fmaxf(mx, __shfl_xor(mx, 2, 4));
        float sum = 0.f;
        #pragma unroll
        for (int i = 0; i < 5; ++i)
            if (i < nt) { sv[i] = __expf(sv[i] - mx); sum += sv[i]; }
        sum += __shfl_xor(sum, 1, 4);
        sum += __shfl_xor(sum, 2, 4);
        const float inv = 1.f / sum;
        #pragma unroll
        for (int i = 0; i < 5; ++i)
            if (i < nt) {
                const int j = (i == 4) ? 16 : (g + i * 4);
                uAs[prow + w + j] = f2bf(sv[i] * inv);
            }
    }
    __syncthreads();

    {
        const int cb = wid * 32;
        const short8 z = {0,0,0,0,0,0,0,0};
        f32x4 d00 = {0.f,0.f,0.f,0.f}, d01 = d00, d10 = d00, d11 = d00;
        #pragma unroll
        for (int kk = 0; kk < 2; ++kk) {
            const int koff = kk * 32 + lgrp * 8;
            const bool live = (koff < TWH);
            short8 a0 = z, a1 = z, b0 = z, b1 = z;
            if (live) {
                a0 = *(const short8*)&fA[cb + lrow     ][koff];
                a1 = *(const short8*)&fA[cb + 16 + lrow][koff];
                b0 = *(const short8*)(uAs + lrow * PTPF + koff);
                b1 = *(const short8*)(uAs + PT_HIF + lrow * PTPF + koff);
            }
            d00 = __builtin_amdgcn_mfma_f32_16x16x32_bf16(a0, b0, d00, 0, 0, 0);
            d01 = __builtin_amdgcn_mfma_f32_16x16x32_bf16(a0, b1, d01, 0, 0, 0);
            d10 = __builtin_amdgcn_mfma_f32_16x16x32_bf16(a1, b0, d10, 0, 0, 0);
            d11 = __builtin_amdgcn_mfma_f32_16x16x32_bf16(a1, b1, d11, 0, 0, 0);
        }
        const int wbase = wt * TW;
        #pragma unroll
        for (int reg = 0; reg < 4; ++reg) {
            const int c0 = cb + lgrp * 4 + reg;
            out[base + c0 * (HH * WW)        + wbase + lrow]      = d00[reg];
            out[base + c0 * (HH * WW)        + wbase + 16 + lrow] = d01[reg];
            out[base + (c0 + 16) * (HH * WW) + wbase + lrow]      = d10[reg];
            out[base + (c0 + 16) * (HH * WW) + wbase + 16 + lrow] = d11[reg];
        }
    }
}

extern "C" void kernel_launch(void* const* d_in, const int* in_sizes, int n_in,
                              void* d_out, int out_size, void* d_ws, size_t ws_size,
                              hipStream_t stream) {
    const float* feature  = (const float*)d_in[0];
    const float* position = (const float*)d_in[1];
    const float* Wq = (const float*)d_in[2];
    const float* bq = (const float*)d_in[3];
    const float* Wk = (const float*)d_in[4];
    const float* bk = (const float*)d_in[5];   // only row-const softmax terms
    (void)bk;
    float* out = (float*)d_out;
    char*  ws  = (char*)d_ws;
    short* Mp  = (short*)ws;

    prep_kernel<<<MROWS, 128, 0, stream>>>(Wq, bq, Wk, Mp);

    if (ws_size >= WS_NEED) {
        short* fTg = (short*)(ws + OFF_FT);
        short* gTg = (short*)(ws + OFF_GT);
        short* fNg = (short*)(ws + OFF_FN);
        float* ubg = (float*)(ws + OFF_UB);
        k1_transform<<<dim3(BB * HH * (WW / 64)), NTHREADS, 0, stream>>>(
            feature, position, Mp, fTg, gTg, fNg, ubg);
        k2_attn<<<dim3(BB * HH * (WW / TW)), NTHREADS, 0, stream>>>(
            fTg, gTg, fNg, ubg, out);
    } else {
        attn1d_fused<<<dim3(BB * HH * (WW / TW)), NTHREADS, 0, stream>>>(
            feature, position, Mp, out);
    }
}

// Round 11
// 40.774 us; speedup vs baseline: 1.3548x; 1.3548x over previous
//
#include <hip/hip_runtime.h>
#include <hip/hip_bf16.h>
#include <math.h>

#define BB 4
#define CCH 128     // channels
#define HH 64
#define WW 256
#define RR 8
#define KWIN 17
#define TW 32       // output w-tile per block
#define TWH 48      // TW + 2R (halo)
#define NTHREADS 256
#define PIT 136     // fBt/gT pitch (shorts)
#define FAP 48      // fA pitch (shorts)
#define PTP 48      // Pt pitch (shorts)
#define PT_HI 5440  // short offset of Pt rows 16..31 inside uA
#define MROWS 144

typedef __attribute__((ext_vector_type(8))) short short8;
typedef __attribute__((ext_vector_type(4))) short short4v;
typedef __attribute__((ext_vector_type(4))) float f32x4;

__device__ __forceinline__ short f2bf(float x) {
    union { __hip_bfloat16 b; short s; } u;
    u.b = __float2bfloat16(x);
    return u.s;
}

// ---- prep: M' bf16 [144][128] = [Wq^T Wk ; (Wk^T bq)^T ; zeros] into d_ws ----
__global__ __launch_bounds__(128)
void prep_kernel(const float* __restrict__ Wq, const float* __restrict__ bq,
                 const float* __restrict__ Wk, short* __restrict__ Mp)
{
    const int r = blockIdx.x;      // 0..143
    const int c = threadIdx.x;     // 0..127
    float acc = 0.f;
    if (r < CCH) {
        #pragma unroll 4
        for (int j = 0; j < CCH; ++j)
            acc = fmaf(Wq[j * CCH + r], Wk[j * CCH + c], acc);
    } else if (r == CCH) {
        #pragma unroll 4
        for (int o = 0; o < CCH; ++o)
            acc = fmaf(bq[o], Wk[o * CCH + c], acc);
    }
    Mp[r * CCH + c] = f2bf(acc);
}

// St embedded in gT region: St row r lives inside the 16-row gT block (r>>4)
// that only wave (r>>4) reads -> write-after-own-read, no cross-wave race.
#define ST_IDX(r) (((r) >> 4) * 1088 + ((r) & 15) * 36)   // float index into uB

__global__ __launch_bounds__(NTHREADS, 4)
void attn1d_fused(const float* __restrict__ feature,
                  const float* __restrict__ position,
                  const short* __restrict__ Mp,
                  float* __restrict__ out)
{
    // uA: fBt [48][136] (stage->C); Pt overlays fBt rows 0..7 / 40..47 (C-dead)
    // uB: gT [48][136] (B->C); St embedded per-16-row block (C->softmax)
    __shared__ __align__(16) char uA[TWH * PIT * 2];     // 13056
    __shared__ __align__(16) char uB[TWH * PIT * 2];     // 13056
    __shared__ __align__(16) short fA[CCH][FAP];         // 12288  f [c][wl]
    __shared__ float ubias[TWH];                         //   192
                                                         // total 38592 -> 4 blocks/CU
    short (*fBt)[PIT] = (short(*)[PIT])uA;
    short (*gT)[PIT]  = (short(*)[PIT])uB;
    float* Stp        = (float*)uB;
    short* uAs        = (short*)uA;

    const int t    = threadIdx.x;
    const int wid  = t >> 6;
    const int lane = t & 63;
    const int lrow = lane & 15;
    const int lgrp = lane >> 4;

    // XCD-chunked bijective swizzle (2048 % 8 == 0)
    int blk = blockIdx.x;
    blk = (blk & 7) * 256 + (blk >> 3);
    const int wt = blk & 7;
    const int bh = blk >> 3;
    const int h  = bh & (HH - 1);
    const int b  = bh >> 6;
    const int w0 = wt * TW - RR;
    const int base = ((b * CCH) * HH + h) * WW;

    // ---------------- Phase A: stage f (c-pair, packed u32 fBt writes) -------
    // idx = i*256+t; cp = idx/12 (c-pair 0..63), wq = idx%12. Loads of rows
    // 2cp and 2cp+1 stay 192B-contiguous per 12-lane run (proven coalescing);
    // the u32 write packs (c,c+1) which are naturally adjacent in fBt ->
    // reads unchanged, write instruction count halved, ~cp-granular banks.
    #pragma unroll
    for (int i = 0; i < 3; ++i) {
        const int idx = i * NTHREADS + t;        // 0..767
        const int cp  = idx / 12;
        const int wq  = idx - cp * 12;
        const int c0  = cp * 2;
        const int w   = w0 + wq * 4;             // quad fully in or out (w0 % 4 == 0)
        float4 fv0 = {0.f,0.f,0.f,0.f}, fv1 = {0.f,0.f,0.f,0.f};
        if (w >= 0 && w < WW) {
            const int off = base + c0 * (HH * WW) + w;
            const float4 fa0 = *(const float4*)(feature + off);
            const float4 pa0 = *(const float4*)(position + off);
            const float4 fa1 = *(const float4*)(feature + off + HH * WW);
            const float4 pa1 = *(const float4*)(position + off + HH * WW);
            fv0.x = fa0.x + pa0.x; fv0.y = fa0.y + pa0.y;
            fv0.z = fa0.z + pa0.z; fv0.w = fa0.w + pa0.w;
            fv1.x = fa1.x + pa1.x; fv1.y = fa1.y + pa1.y;
            fv1.z = fa1.z + pa1.z; fv1.w = fa1.w + pa1.w;
        }
        short4v s0, s1;
        s0[0] = f2bf(fv0.x); s0[1] = f2bf(fv0.y); s0[2] = f2bf(fv0.z); s0[3] = f2bf(fv0.w);
        s1[0] = f2bf(fv1.x); s1[1] = f2bf(fv1.y); s1[2] = f2bf(fv1.z); s1[3] = f2bf(fv1.w);
        *(short4v*)&fA[c0    ][wq * 4] = s0;
        *(short4v*)&fA[c0 + 1][wq * 4] = s1;
        #pragma unroll
        for (int j = 0; j < 4; ++j) {
            const unsigned uv = (unsigned)(unsigned short)s0[j]
                              | ((unsigned)(unsigned short)s1[j] << 16);
            *(unsigned*)&fBt[wq * 4 + j][c0] = uv;
        }
    }

    // ---- M-fragments from ws (bf16, direct 16B loads; L2-hot broadcast) ------
    const int mrow = wid * 32;
    short8 Mf[2][4];            // [mf][kk] rows mrow..mrow+31
    #pragma unroll
    for (int mf = 0; mf < 2; ++mf)
        #pragma unroll
        for (int kk = 0; kk < 4; ++kk)
            Mf[mf][kk] = *(const short8*)(Mp + (mrow + mf * 16 + lrow) * CCH
                                             + kk * 32 + lgrp * 8);
    short8 Mf2[4];              // wave 3 only: u-row 128
    if (wid == 3) {
        #pragma unroll
        for (int kk = 0; kk < 4; ++kk)
            Mf2[kk] = *(const short8*)(Mp + (CCH + lrow) * CCH + kk * 32 + lgrp * 8);
    }
    __syncthreads();

    // ---------------- Phase B: g = M f via MFMA (all 4 waves, 32 rows each) ---
    {
        f32x4 acc[2][3];
        #pragma unroll
        for (int mf = 0; mf < 2; ++mf)
            #pragma unroll
            for (int nf = 0; nf < 3; ++nf)
                acc[mf][nf] = (f32x4){0.f, 0.f, 0.f, 0.f};
        f32x4 acc2[3];
        #pragma unroll
        for (int nf = 0; nf < 3; ++nf) acc2[nf] = (f32x4){0.f, 0.f, 0.f, 0.f};

        #pragma unroll
        for (int kk = 0; kk < 4; ++kk) {
            short8 bfr[3];
            #pragma unroll
            for (int nf = 0; nf < 3; ++nf)
                bfr[nf] = *(const short8*)&fBt[nf * 16 + lrow][kk * 32 + lgrp * 8];
            #pragma unroll
            for (int mf = 0; mf < 2; ++mf)
                #pragma unroll
                for (int nf = 0; nf < 3; ++nf)
                    acc[mf][nf] = __builtin_amdgcn_mfma_f32_16x16x32_bf16(
                        Mf[mf][kk], bfr[nf], acc[mf][nf], 0, 0, 0);
            if (wid == 3) {
                #pragma unroll
                for (int nf = 0; nf < 3; ++nf)
                    acc2[nf] = __builtin_amdgcn_mfma_f32_16x16x32_bf16(
                        Mf2[kk], bfr[nf], acc2[nf], 0, 0, 0);
            }
        }

        // writeback g^T (bf16): rows wl = nf*16+lrow, cols mrow+mf*16+lgrp*4+reg
        #pragma unroll
        for (int mf = 0; mf < 2; ++mf)
            #pragma unroll
            for (int nf = 0; nf < 3; ++nf) {
                short4v s;
                #pragma unroll
                for (int reg = 0; reg < 4; ++reg)
                    s[reg] = f2bf(acc[mf][nf][reg]);
                *(short4v*)&gT[nf * 16 + lrow][mrow + mf * 16 + lgrp * 4] = s;
            }
        if (wid == 3 && lgrp == 0) {
            const float isc = 0.08838834764831845f;
            #pragma unroll
            for (int nf = 0; nf < 3; ++nf)
                ubias[nf * 16 + lrow] = acc2[nf][0] * isc;
        }
    }
    __syncthreads();

    // ---------------- Phase C: S^T = (f^T g) / sqrt(C) via MFMA ---------------
    if (wid < 3) {
        const int nf = wid;          // wl' block 0..2
        f32x4 s0 = {0.f,0.f,0.f,0.f}, s1 = {0.f,0.f,0.f,0.f};
        #pragma unroll
        for (int kk = 0; kk < 4; ++kk) {
            const short8 a0 = *(const short8*)&fBt[RR + lrow     ][kk * 32 + lgrp * 8];
            const short8 a1 = *(const short8*)&fBt[RR + 16 + lrow][kk * 32 + lgrp * 8];
            const short8 bb = *(const short8*)&gT[nf * 16 + lrow][kk * 32 + lgrp * 8];
            s0 = __builtin_amdgcn_mfma_f32_16x16x32_bf16(a0, bb, s0, 0, 0, 0);
            s1 = __builtin_amdgcn_mfma_f32_16x16x32_bf16(a1, bb, s1, 0, 0, 0);
        }
        const float isc = 0.08838834764831845f;   // 1/sqrt(128)
        const int sb = ST_IDX(nf * 16 + lrow);    // write inside own gT block
        *(f32x4*)&Stp[sb + lgrp * 4]      = s0 * isc;
        *(f32x4*)&Stp[sb + 16 + lgrp * 4] = s1 * isc;
    } else {
        // wave 3: zero-fill Pt (overlay in fBt rows 0..7 / 40..47, C-dead)
        const short8 z = {0,0,0,0,0,0,0,0};
        #pragma unroll
        for (int i = 0; i < 2; ++i) {
            const int q8 = i * 64 + lane;         // 96 short8 per half
            if (q8 < 96) {
                *(short8*)(uAs + q8 * 8) = z;            // Pt rows 0..15
                *(short8*)(uAs + PT_HI + q8 * 8) = z;    // Pt rows 16..31
            }
        }
    }
    __syncthreads();

    // ---------------- softmax over 17 taps (8 threads/row, all 256) ----------
    {
        const int w = t >> 3, g = t & 7;
        const int nt = (g == 0) ? 3 : 2;          // taps j = g, g+8, (g==0 -> 16)
        const int prow = (w < 16) ? (w * PTP) : (PT_HI + (w - 16) * PTP);
        float sv[3];
        float mx = -3.0e38f;
        #pragma unroll
        for (int i = 0; i < 3; ++i) {
            if (i < nt) {
                const int j = (i == 2) ? 16 : (g + i * 8);
                const int r = w + j;
                sv[i] = Stp[ST_IDX(r) + w] + ubias[r];
                mx = fmaxf(mx, sv[i]);
            }
        }
        mx = fmaxf(mx, __shfl_xor(mx, 1, 8));
        mx = fmaxf(mx, __shfl_xor(mx, 2, 8));
        mx = fmaxf(mx, __shfl_xor(mx, 4, 8));
        float sum = 0.f;
        #pragma unroll
        for (int i = 0; i < 3; ++i)
            if (i < nt) { sv[i] = __expf(sv[i] - mx); sum += sv[i]; }
        sum += __shfl_xor(sum, 1, 8);
        sum += __shfl_xor(sum, 2, 8);
        sum += __shfl_xor(sum, 4, 8);
        const float inv = 1.f / sum;
        #pragma unroll
        for (int i = 0; i < 3; ++i)
            if (i < nt) {
                const int j = (i == 2) ? 16 : (g + i * 8);
                uAs[prow + w + j] = f2bf(sv[i] * inv);
            }
    }
    __syncthreads();

    // ---------------- Phase D: out = f . P^T via MFMA -------------------------
    // kk=1 & lgrp>=2 -> k-cols 48..63: both operands substituted zero.
    {
        const int cb = wid * 32;
        const short8 z = {0,0,0,0,0,0,0,0};
        f32x4 d00 = {0.f,0.f,0.f,0.f}, d01 = d00, d10 = d00, d11 = d00;
        #pragma unroll
        for (int kk = 0; kk < 2; ++kk) {
            const int koff = kk * 32 + lgrp * 8;
            const bool live = (koff < TWH);
            short8 a0 = z, a1 = z, b0 = z, b1 = z;
            if (live) {
                a0 = *(const short8*)&fA[cb + lrow     ][koff];
                a1 = *(const short8*)&fA[cb + 16 + lrow][koff];
                b0 = *(const short8*)(uAs + lrow * PTP + koff);           // Pt 0..15
                b1 = *(const short8*)(uAs + PT_HI + lrow * PTP + koff);   // Pt 16..31
            }
            d00 = __builtin_amdgcn_mfma_f32_16x16x32_bf16(a0, b0, d00, 0, 0, 0);
            d01 = __builtin_amdgcn_mfma_f32_16x16x32_bf16(a0, b1, d01, 0, 0, 0);
            d10 = __builtin_amdgcn_mfma_f32_16x16x32_bf16(a1, b0, d10, 0, 0, 0);
            d11 = __builtin_amdgcn_mfma_f32_16x16x32_bf16(a1, b1, d11, 0, 0, 0);
        }
        const int wbase = wt * TW;
        #pragma unroll
        for (int reg = 0; reg < 4; ++reg) {
            const int c0 = cb + lgrp * 4 + reg;
            out[base + c0 * (HH * WW)        + wbase + lrow]      = d00[reg];
            out[base + c0 * (HH * WW)        + wbase + 16 + lrow] = d01[reg];
            out[base + (c0 + 16) * (HH * WW) + wbase + lrow]      = d10[reg];
            out[base + (c0 + 16) * (HH * WW) + wbase + 16 + lrow] = d11[reg];
        }
    }
}

extern "C" void kernel_launch(void* const* d_in, const int* in_sizes, int n_in,
                              void* d_out, int out_size, void* d_ws, size_t ws_size,
                              hipStream_t stream) {
    const float* feature  = (const float*)d_in[0];
    const float* position = (const float*)d_in[1];
    const float* Wq = (const float*)d_in[2];
    const float* bq = (const float*)d_in[3];
    const float* Wk = (const float*)d_in[4];
    const float* bk = (const float*)d_in[5];   // only row-const softmax terms
    (void)bk;
    float* out = (float*)d_out;
    short* Mp  = (short*)d_ws;                 // 144x128 bf16 = 36864 B

    prep_kernel<<<MROWS, 128, 0, stream>>>(Wq, bq, Wk, Mp);
    const dim3 grid(BB * HH * (WW / TW));      // 2048 blocks, 4/CU -> 2 exact rounds
    attn1d_fused<<<grid, NTHREADS, 0, stream>>>(feature, position, Mp, out);
}